// Round 10
// baseline (561.130 us; speedup 1.0000x reference)
//
#include <hip/hip_runtime.h>

#define NN 50000
#define NE 800000
#define NG 64
#define EPSF 1e-5f

typedef __bf16 bf16x8 __attribute__((ext_vector_type(8)));
typedef float f32x4 __attribute__((ext_vector_type(4)));

#define AS1 __attribute__((address_space(1)))
#define AS3 __attribute__((address_space(3)))

__device__ __forceinline__ void gl_lds16(const unsigned short* g, unsigned short* l) {
#if __has_builtin(__builtin_amdgcn_global_load_lds)
  __builtin_amdgcn_global_load_lds((const AS1 void*)g, (AS3 void*)l, 16, 0, 0);
#else
  *(uint4*)l = *(const uint4*)g;
#endif
}

__device__ __forceinline__ unsigned short f2bf(float f) {
  unsigned u = __builtin_bit_cast(unsigned, f);
  u += 0x7fff + ((u >> 16) & 1);  // RNE
  return (unsigned short)(u >> 16);
}
__device__ __forceinline__ float bf_lo(unsigned u) {
  return __builtin_bit_cast(float, u << 16);
}
__device__ __forceinline__ float bf_hi(unsigned u) {
  return __builtin_bit_cast(float, u & 0xffff0000u);
}

// ---------------- fused prep: deg+rank atomics | x->bf16 | weights->bf16^T ----------------
#define DEGB 3125   // = NE/256
#define XB   6250   // = NN*128/4/256
#define WTB  1024   // = 262144/256
__global__ void prep_kernel(const int* __restrict__ src, const int* __restrict__ dst,
                            int* __restrict__ dout, int* __restrict__ din,
                            int* __restrict__ rank,
                            const float* __restrict__ x, unsigned short* __restrict__ xb,
                            const float* __restrict__ W1, const float* __restrict__ Wfc,
                            const float* __restrict__ W2, const float* __restrict__ W3,
                            unsigned short* __restrict__ W1t, unsigned short* __restrict__ Wfct,
                            unsigned short* __restrict__ W2t, unsigned short* __restrict__ W3t) {
  int b = blockIdx.x;
  if (b < DEGB) {
    int e = b * 256 + threadIdx.x;
    atomicAdd(&dout[src[e]], 1);
    rank[e] = atomicAdd(&din[dst[e]], 1);
  } else if (b < DEGB + XB) {
    int i = (b - DEGB) * 256 + threadIdx.x;
    float4 v = ((const float4*)x)[i];
    uint2 pk;
    pk.x = (unsigned)f2bf(v.x) | ((unsigned)f2bf(v.y) << 16);
    pk.y = (unsigned)f2bf(v.z) | ((unsigned)f2bf(v.w) << 16);
    ((uint2*)xb)[i] = pk;
  } else {
    int i = (b - DEGB - XB) * 256 + threadIdx.x;  // 0..262143
    const float* W; unsigned short* Wt; int K, local;
    if (i < 32768)       { W = W1;  Wt = W1t;  K = 128; local = i; }
    else if (i < 65536)  { W = Wfc; Wt = Wfct; K = 128; local = i - 32768; }
    else if (i < 196608) { W = W2;  Wt = W2t;  K = 512; local = i - 65536; }
    else                 { W = W3;  Wt = W3t;  K = 256; local = i - 196608; }
    int n = local / K, k = local - n * K;
    Wt[local] = f2bf(W[(size_t)k * 256 + n]);
  }
}

// ---------------- norms + scan phase 1 ----------------
__global__ void norms_scan1(const int* __restrict__ dout, const int* __restrict__ din,
                            float* __restrict__ onorm, float* __restrict__ inorm,
                            int* __restrict__ bsum, int n) {
  int i = blockIdx.x * 256 + threadIdx.x;
  int d = 0;
  if (i < n) {
    int a = dout[i];
    d = din[i];
    onorm[i] = rsqrtf((float)(a > 1 ? a : 1));
    inorm[i] = rsqrtf((float)(d > 1 ? d : 1));
  }
  int v = d;
#pragma unroll
  for (int off = 32; off > 0; off >>= 1) v += __shfl_down(v, off);
  __shared__ int ws[4];
  int wave = threadIdx.x >> 6, lane = threadIdx.x & 63;
  if (lane == 0) ws[wave] = v;
  __syncthreads();
  if (threadIdx.x == 0) bsum[blockIdx.x] = ws[0] + ws[1] + ws[2] + ws[3];
}

__global__ void scan2_kernel(const int* __restrict__ bsum, int* __restrict__ boff,
                             int nb, int* __restrict__ rp, int n) {
  int t = threadIdx.x;
  int v = (t < nb) ? bsum[t] : 0;
  __shared__ int tmp[256];
  tmp[t] = v;
  __syncthreads();
  for (int off = 1; off < 256; off <<= 1) {
    int x = (t >= off) ? tmp[t - off] : 0;
    __syncthreads();
    tmp[t] += x;
    __syncthreads();
  }
  if (t < nb) boff[t] = tmp[t] - v;
  if (t == 255) rp[n] = tmp[255];
}

__global__ void scan3_kernel(const int* __restrict__ din, const int* __restrict__ boff,
                             int* __restrict__ rp, int n) {
  int t = threadIdx.x;
  int i = blockIdx.x * 256 + t;
  int v = (i < n) ? din[i] : 0;
  __shared__ int tmp[256];
  tmp[t] = v;
  __syncthreads();
  for (int off = 1; off < 256; off <<= 1) {
    int x = (t >= off) ? tmp[t - off] : 0;
    __syncthreads();
    tmp[t] += x;
    __syncthreads();
  }
  if (i < n) rp[i] = tmp[t] - v + boff[blockIdx.x];
}

// ---------------- CSR fill, atomic-free; wse = w * onorm[src] * inorm[dst] ----------------
__global__ void fill_kernel(const int* __restrict__ src, const int* __restrict__ dst,
                            const float* __restrict__ w, const float* __restrict__ onorm,
                            const float* __restrict__ inorm,
                            const int* __restrict__ rp, const int* __restrict__ rank,
                            int* __restrict__ col, float* __restrict__ wse, int E) {
  int e = blockIdx.x * 256 + threadIdx.x;
  if (e < E) {
    int d = dst[e], s = src[e];
    int pos = rp[d] + rank[e];
    col[pos] = s;
    wse[pos] = w[e] * onorm[s] * inorm[d];
  }
}

// ---------------- per-wave SpMM body (R5-best form + 8-edge unroll) ----------------
// One wave handles node v; lane covers 2*NU feats via uint/uint2 loads.
template <int RELU, int NU>
__device__ __forceinline__ void spmm_wave(
    const unsigned short* __restrict__ feat, int ldf,
    const int* __restrict__ rp, const int* __restrict__ col,
    const float* __restrict__ wse,
    unsigned short* __restrict__ out, int ldo, int v, int lane) {
  int beg = rp[v], end = rp[v + 1];
  float acc[2 * NU];
#pragma unroll
  for (int i = 0; i < 2 * NU; i++) acc[i] = 0.f;
  const unsigned short* base = feat + lane * (2 * NU);
  int e = beg;
  for (; e + 8 <= end; e += 8) {
    int s[8]; float ww[8];
#pragma unroll
    for (int k = 0; k < 8; k++) { s[k] = col[e + k]; ww[k] = wse[e + k]; }
    unsigned u[8][NU];
#pragma unroll
    for (int k = 0; k < 8; k++) {
      const unsigned* pr = (const unsigned*)&base[(size_t)s[k] * ldf];
      if (NU == 2) { uint2 q = *(const uint2*)pr; u[k][0] = q.x; u[k][NU - 1] = q.y; }
      else u[k][0] = pr[0];
    }
#pragma unroll
    for (int k = 0; k < 8; k++)
#pragma unroll
      for (int j = 0; j < NU; j++) {
        acc[2 * j]     += ww[k] * bf_lo(u[k][j]);
        acc[2 * j + 1] += ww[k] * bf_hi(u[k][j]);
      }
  }
  for (; e < end; e++) {
    float w0 = wse[e];
    const unsigned* pr = (const unsigned*)&base[(size_t)col[e] * ldf];
    unsigned u[NU];
    if (NU == 2) { uint2 q = *(const uint2*)pr; u[0] = q.x; u[NU - 1] = q.y; }
    else u[0] = pr[0];
#pragma unroll
    for (int j = 0; j < NU; j++) {
      acc[2 * j]     += w0 * bf_lo(u[j]);
      acc[2 * j + 1] += w0 * bf_hi(u[j]);
    }
  }
  unsigned o[NU];
#pragma unroll
  for (int j = 0; j < NU; j++) {
    float a = acc[2 * j], b = acc[2 * j + 1];
    if (RELU) { a = fmaxf(a, 0.f); b = fmaxf(b, 0.f); }
    o[j] = (unsigned)f2bf(a) | ((unsigned)f2bf(b) << 16);
  }
  unsigned* po = (unsigned*)&out[(size_t)v * ldo + lane * (2 * NU)];
  if (NU == 2) *(uint2*)po = make_uint2(o[0], o[NU - 1]);
  else po[0] = o[0];
}

template <int RELU, int NU>
__global__ __launch_bounds__(64) void spmm_bf16(
    const unsigned short* __restrict__ feat, int ldf,
    const int* __restrict__ rp, const int* __restrict__ col,
    const float* __restrict__ wse,
    unsigned short* __restrict__ out, int ldo) {
  spmm_wave<RELU, NU>(feat, ldf, rp, col, wse, out, ldo, blockIdx.x, threadIdx.x);
}

// ---------------- MFMA GEMM body: BK=32 (proven form), explicit tile coords ----------------
__device__ __forceinline__ void gemm_body(
    const unsigned short* __restrict__ A, int lda,
    const unsigned short* __restrict__ Bt, int K,
    void* __restrict__ Cv, int ldc, int col_off, int M,
    int relu, int out32, int mb, int nb,
    unsigned short* As, unsigned short* Bs) {
  const int tid = threadIdx.x;
  const int lane = tid & 63;
  const int w = tid >> 6;
  const int wm = w >> 1, wn = w & 1;
  const int m0 = mb * 128;
  const int n0 = nb * 128;
  const int q = lane >> 4;
  const int r16 = lane & 15;

  f32x4 acc[4][4];
#pragma unroll
  for (int i = 0; i < 4; i++)
#pragma unroll
    for (int j = 0; j < 4; j++) acc[i][j] = (f32x4){0.f, 0.f, 0.f, 0.f};

  const int ta = 2 * w, tb = 2 * w + 1;
  int gma = m0 + ta * 16 + r16; if (gma >= M) gma = M - 1;
  int gmb = m0 + tb * 16 + r16; if (gmb >= M) gmb = M - 1;
  const int gna = n0 + ta * 16 + r16;
  const int gnb = n0 + tb * 16 + r16;
  const unsigned short* pa = A + (size_t)gma * lda + q * 8;
  const unsigned short* pb = A + (size_t)gmb * lda + q * 8;
  const unsigned short* pc = Bt + (size_t)gna * K + q * 8;
  const unsigned short* pd = Bt + (size_t)gnb * K + q * 8;

  for (int k0 = 0; k0 < K; k0 += 32) {
    __syncthreads();
    gl_lds16(pa + k0, &As[ta * 512 + lane * 8]);
    gl_lds16(pb + k0, &As[tb * 512 + lane * 8]);
    gl_lds16(pc + k0, &Bs[ta * 512 + lane * 8]);
    gl_lds16(pd + k0, &Bs[tb * 512 + lane * 8]);
    __syncthreads();

    bf16x8 af[4], bfr[4];
#pragma unroll
    for (int i = 0; i < 4; i++)
      af[i] = *(const bf16x8*)&As[(wm * 4 + i) * 512 + lane * 8];
#pragma unroll
    for (int j = 0; j < 4; j++)
      bfr[j] = *(const bf16x8*)&Bs[(wn * 4 + j) * 512 + lane * 8];
#pragma unroll
    for (int i = 0; i < 4; i++)
#pragma unroll
      for (int j = 0; j < 4; j++)
        acc[i][j] = __builtin_amdgcn_mfma_f32_16x16x32_bf16(af[i], bfr[j], acc[i][j], 0, 0, 0);
  }

#pragma unroll
  for (int i = 0; i < 4; i++) {
    int rbase = m0 + (wm * 4 + i) * 16 + q * 4;
#pragma unroll
    for (int r = 0; r < 4; r++) {
      int gm = rbase + r;
      if (gm >= M) continue;
#pragma unroll
      for (int j = 0; j < 4; j++) {
        float v = acc[i][j][r];
        if (relu) v = fmaxf(v, 0.f);
        int gn = col_off + n0 + (wn * 4 + j) * 16 + r16;
        if (out32)
          ((float*)Cv)[(size_t)gm * ldc + gn] = v;
        else
          ((unsigned short*)Cv)[(size_t)gm * ldc + gn] = f2bf(v);
      }
    }
  }
}

// ---------------- fused A: spmm1 (blocks 0..12499) | fc-GEMM (blocks 12500..13281) ----------------
#define SPB 12500  // NN/4
__global__ __launch_bounds__(256) void fusedA_kernel(
    const unsigned short* __restrict__ xb,
    const int* __restrict__ rp, const int* __restrict__ col,
    const float* __restrict__ wse,
    unsigned short* __restrict__ aggX,
    const unsigned short* __restrict__ Wfct, unsigned short* __restrict__ x1f1, int M) {
  __shared__ unsigned short As[8 * 512];
  __shared__ unsigned short Bs[8 * 512];
  int b = blockIdx.x;
  if (b < SPB) {
    int wv = threadIdx.x >> 6, lane = threadIdx.x & 63;
    int v = b * 4 + wv;  // < 50000 always
    spmm_wave<0, 1>(xb, 128, rp, col, wse, aggX, 128, v, lane);
  } else {
    int gb = b - SPB;  // 0..781
    gemm_body(xb, 128, Wfct, 128, x1f1, 512, 256, M, 0, 0, gb >> 1, gb & 1, As, Bs);
  }
}

// ---------------- fused B: LayerNorm+relu (blocks 0..49999) | conv1-GEMM ----------------
__global__ __launch_bounds__(256) void fusedB_kernel(
    unsigned short* __restrict__ x1f1,
    const float* __restrict__ gamma, const float* __restrict__ beta,
    const unsigned short* __restrict__ aggX, const unsigned short* __restrict__ W1t, int M) {
  __shared__ unsigned short As[8 * 512];
  __shared__ unsigned short Bs[8 * 512];
  int b = blockIdx.x;
  if (b < NN) {
    // ln_relu on f1pre = x1f1[:, 256:512], ld 512
    unsigned short* h = x1f1 + 256;
    int f = threadIdx.x;
    float val = bf_lo((unsigned)h[(size_t)b * 512 + f]);
    float s = val, qq = val * val;
#pragma unroll
    for (int off = 32; off > 0; off >>= 1) {
      s += __shfl_down(s, off);
      qq += __shfl_down(qq, off);
    }
    __shared__ float ws_[5], wq_[5];
    int wave = f >> 6, lane = f & 63;
    if (lane == 0) { ws_[wave] = s; wq_[wave] = qq; }
    __syncthreads();
    if (f == 0) {
      float S = 0, Q = 0;
      for (int i = 0; i < 4; i++) { S += ws_[i]; Q += wq_[i]; }
      ws_[4] = S; wq_[4] = Q;
    }
    __syncthreads();
    float mean = ws_[4] * (1.f / 256.f);
    float var = wq_[4] * (1.f / 256.f) - mean * mean;
    float y = (val - mean) * rsqrtf(var + EPSF) * gamma[f] + beta[f];
    h[(size_t)b * 512 + f] = f2bf(y > 0.f ? y : 0.f);
  } else {
    int gb = b - NN;  // 0..781
    gemm_body(aggX, 128, W1t, 128, x1f1, 512, 0, M, 1, 0, gb >> 1, gb & 1, As, Bs);
  }
}

__global__ __launch_bounds__(256) void gemm_kernel(
    const unsigned short* __restrict__ A, int lda,
    const unsigned short* __restrict__ Bt, int K,
    void* __restrict__ Cv, int ldc, int M, int relu, int out32) {
  __shared__ unsigned short As[8 * 512];
  __shared__ unsigned short Bs[8 * 512];
  gemm_body(A, lda, Bt, K, Cv, ldc, 0, M, relu, out32, blockIdx.x, blockIdx.y, As, Bs);
}

// ---------------- per-graph readout (graph_ids sorted), x3 fp32 ----------------
__global__ void readout_kernel(const float* __restrict__ x3, const int* __restrict__ gid,
                               float* __restrict__ out, int n) {
  int g = blockIdx.x;
  int part = blockIdx.y;  // 8 parts
  int f = threadIdx.x;    // 256
  int lo = 0, hi = n;
  while (lo < hi) { int mid = (lo + hi) >> 1; if (gid[mid] < g) lo = mid + 1; else hi = mid; }
  int s = lo;
  lo = s; hi = n;
  while (lo < hi) { int mid = (lo + hi) >> 1; if (gid[mid] < g + 1) lo = mid + 1; else hi = mid; }
  int e = lo;
  int len = e - s;
  if (len <= 0) return;
  int chunk = (len + 7) / 8;
  int cs = s + part * chunk;
  int ce = cs + chunk; if (ce > e) ce = e;
  if (cs >= ce) return;
  float acc = 0.f;
  for (int v = cs; v < ce; v++) acc += x3[(size_t)v * 256 + f];
  atomicAdd(&out[g * 256 + f], acc);
}

// ---------------- launch ----------------

extern "C" void kernel_launch(void* const* d_in, const int* in_sizes, int n_in,
                              void* d_out, int out_size, void* d_ws, size_t ws_size,
                              hipStream_t stream) {
  const float* x     = (const float*)d_in[0];
  const float* w     = (const float*)d_in[1];
  const float* W1    = (const float*)d_in[2];
  const float* Wfc   = (const float*)d_in[3];
  const float* gamma = (const float*)d_in[4];
  const float* beta  = (const float*)d_in[5];
  const float* W2    = (const float*)d_in[6];
  const float* W3    = (const float*)d_in[7];
  const int*   src   = (const int*)d_in[8];
  const int*   dst   = (const int*)d_in[9];
  const int*   gid   = (const int*)d_in[10];
  float* out = (float*)d_out;

  const int N = NN, E = NE;

  char* p = (char*)d_ws;
  auto alloc = [&](size_t bytes) {
    char* r = p;
    p += (bytes + 255) & ~(size_t)255;
    return r;
  };
  int*   deg_out = (int*)alloc((size_t)N * 4);
  int*   deg_in  = (int*)alloc((size_t)N * 4);   // contiguous after deg_out
  float* onorm   = (float*)alloc((size_t)N * 4);
  float* inorm   = (float*)alloc((size_t)N * 4);
  int*   row_ptr = (int*)alloc((size_t)(N + 1) * 4);
  int*   bsum    = (int*)alloc(256 * 4);
  int*   boff    = (int*)alloc(256 * 4);
  int*   rank    = (int*)alloc((size_t)E * 4);
  int*   col     = (int*)alloc((size_t)E * 4);
  float* wse     = (float*)alloc((size_t)E * 4);
  unsigned short* xb    = (unsigned short*)alloc((size_t)N * 128 * 2);
  unsigned short* aggX  = (unsigned short*)alloc((size_t)N * 128 * 2);
  unsigned short* x1f1  = (unsigned short*)alloc((size_t)N * 512 * 2);
  unsigned short* y2    = (unsigned short*)alloc((size_t)N * 256 * 2);
  unsigned short* x2    = (unsigned short*)alloc((size_t)N * 256 * 2);
  unsigned short* aggx2 = (unsigned short*)alloc((size_t)N * 256 * 2);
  unsigned short* W1t   = (unsigned short*)alloc((size_t)256 * 128 * 2);
  unsigned short* Wfct  = (unsigned short*)alloc((size_t)256 * 128 * 2);
  unsigned short* W2t   = (unsigned short*)alloc((size_t)256 * 512 * 2);
  unsigned short* W3t   = (unsigned short*)alloc((size_t)256 * 256 * 2);
  float* x3 = (float*)x1f1;  // x1f1 dead after y2 GEMM; reuse storage

  hipMemsetAsync(deg_out, 0, (size_t)((char*)onorm - (char*)deg_out), stream);
  hipMemsetAsync(out, 0, (size_t)NG * 256 * 4, stream);

  const int nbS = (N + 255) / 256;  // 196

  prep_kernel<<<DEGB + XB + WTB, 256, 0, stream>>>(src, dst, deg_out, deg_in, rank,
                                                   x, xb, W1, Wfc, W2, W3,
                                                   W1t, Wfct, W2t, W3t);
  norms_scan1<<<nbS, 256, 0, stream>>>(deg_out, deg_in, onorm, inorm, bsum, N);
  scan2_kernel<<<1, 256, 0, stream>>>(bsum, boff, nbS, row_ptr, N);
  scan3_kernel<<<nbS, 256, 0, stream>>>(deg_in, boff, row_ptr, N);
  fill_kernel<<<(E + 255) / 256, 256, 0, stream>>>(src, dst, w, onorm, inorm, row_ptr,
                                                   rank, col, wse, E);

  dim3 ggrid((N + 127) / 128, 2);  // 391 x 2

  // fused: spmm1 (aggX = agg(xb)) || fc-GEMM (f1pre = xb@Wfc -> x1f1[:,256:512])
  fusedA_kernel<<<SPB + 782, 256, 0, stream>>>(xb, row_ptr, col, wse, aggX, Wfct, x1f1, N);
  // fused: ln_relu(f1pre) in place || conv1-GEMM (x1 = relu(aggX@W1) -> x1f1[:,0:256])
  fusedB_kernel<<<NN + 782, 256, 0, stream>>>(x1f1, gamma, beta, aggX, W1t, N);
  // y2 = x1f1 @ W2
  gemm_kernel<<<ggrid, 256, 0, stream>>>(x1f1, 512, W2t, 512, y2, 256, N, 0, 0);
  // x2 = relu(agg'(y2))
  spmm_bf16<1, 2><<<N, 64, 0, stream>>>(y2, 256, row_ptr, col, wse, x2, 256);
  // aggx2 = agg'(x2)
  spmm_bf16<0, 2><<<N, 64, 0, stream>>>(x2, 256, row_ptr, col, wse, aggx2, 256);
  // x3 = relu(aggx2 @ W3) fp32
  gemm_kernel<<<ggrid, 256, 0, stream>>>(aggx2, 256, W3t, 256, x3, 256, N, 1, 1);
  // readout
  readout_kernel<<<dim3(NG, 8), 256, 0, stream>>>(x3, gid, out, N);
}

// Round 11
// 515.088 us; speedup vs baseline: 1.0894x; 1.0894x over previous
//
#include <hip/hip_runtime.h>

#define NN 50000
#define NE 800000
#define NG 64
#define EPSF 1e-5f

typedef __bf16 bf16x8 __attribute__((ext_vector_type(8)));
typedef float f32x4 __attribute__((ext_vector_type(4)));

#define AS1 __attribute__((address_space(1)))
#define AS3 __attribute__((address_space(3)))

__device__ __forceinline__ void gl_lds16(const unsigned short* g, unsigned short* l) {
#if __has_builtin(__builtin_amdgcn_global_load_lds)
  __builtin_amdgcn_global_load_lds((const AS1 void*)g, (AS3 void*)l, 16, 0, 0);
#else
  *(uint4*)l = *(const uint4*)g;
#endif
}

__device__ __forceinline__ unsigned short f2bf(float f) {
  unsigned u = __builtin_bit_cast(unsigned, f);
  u += 0x7fff + ((u >> 16) & 1);  // RNE
  return (unsigned short)(u >> 16);
}
__device__ __forceinline__ float bf_lo(unsigned u) {
  return __builtin_bit_cast(float, u << 16);
}
__device__ __forceinline__ float bf_hi(unsigned u) {
  return __builtin_bit_cast(float, u & 0xffff0000u);
}

// ---------------- fused prep: deg+rank atomics | x->bf16 | weights->bf16^T ----------------
// All paths ~8 VGPR: matched resources (fusion lesson from R10).
#define DEGB 3125   // = NE/256
#define XB   6250   // = NN*128/4/256
#define WTB  1024   // = 262144/256
__global__ void prep_kernel(const int* __restrict__ src, const int* __restrict__ dst,
                            int* __restrict__ dout, int* __restrict__ din,
                            int* __restrict__ rank,
                            const float* __restrict__ x, unsigned short* __restrict__ xb,
                            const float* __restrict__ W1, const float* __restrict__ Wfc,
                            const float* __restrict__ W2, const float* __restrict__ W3,
                            unsigned short* __restrict__ W1t, unsigned short* __restrict__ Wfct,
                            unsigned short* __restrict__ W2t, unsigned short* __restrict__ W3t) {
  int b = blockIdx.x;
  if (b < DEGB) {
    int e = b * 256 + threadIdx.x;
    atomicAdd(&dout[src[e]], 1);
    rank[e] = atomicAdd(&din[dst[e]], 1);
  } else if (b < DEGB + XB) {
    int i = (b - DEGB) * 256 + threadIdx.x;
    float4 v = ((const float4*)x)[i];
    uint2 pk;
    pk.x = (unsigned)f2bf(v.x) | ((unsigned)f2bf(v.y) << 16);
    pk.y = (unsigned)f2bf(v.z) | ((unsigned)f2bf(v.w) << 16);
    ((uint2*)xb)[i] = pk;
  } else {
    int i = (b - DEGB - XB) * 256 + threadIdx.x;  // 0..262143
    const float* W; unsigned short* Wt; int K, local;
    if (i < 32768)       { W = W1;  Wt = W1t;  K = 128; local = i; }
    else if (i < 65536)  { W = Wfc; Wt = Wfct; K = 128; local = i - 32768; }
    else if (i < 196608) { W = W2;  Wt = W2t;  K = 512; local = i - 65536; }
    else                 { W = W3;  Wt = W3t;  K = 256; local = i - 196608; }
    int n = local / K, k = local - n * K;
    Wt[local] = f2bf(W[(size_t)k * 256 + n]);
  }
}

// ---------------- norms + scan phase 1 ----------------
__global__ void norms_scan1(const int* __restrict__ dout, const int* __restrict__ din,
                            float* __restrict__ onorm, float* __restrict__ inorm,
                            int* __restrict__ bsum, int n) {
  int i = blockIdx.x * 256 + threadIdx.x;
  int d = 0;
  if (i < n) {
    int a = dout[i];
    d = din[i];
    onorm[i] = rsqrtf((float)(a > 1 ? a : 1));
    inorm[i] = rsqrtf((float)(d > 1 ? d : 1));
  }
  int v = d;
#pragma unroll
  for (int off = 32; off > 0; off >>= 1) v += __shfl_down(v, off);
  __shared__ int ws[4];
  int wave = threadIdx.x >> 6, lane = threadIdx.x & 63;
  if (lane == 0) ws[wave] = v;
  __syncthreads();
  if (threadIdx.x == 0) bsum[blockIdx.x] = ws[0] + ws[1] + ws[2] + ws[3];
}

// ---------------- scan phase 2+3 fused: each block redundantly scans bsum ----------------
__global__ void scan3_kernel(const int* __restrict__ din, const int* __restrict__ bsum,
                             int* __restrict__ rp, int n, int nb) {
  int t = threadIdx.x;
  int lane = t & 63, wave = t >> 6;
  // base = sum_{j < blockIdx.x} bsum[j]; tot = sum_j bsum[j] (nb <= 256)
  int bj = (t < nb) ? bsum[t] : 0;
  int pre = (t < (int)blockIdx.x) ? bj : 0;
  int p = pre, q = bj;
#pragma unroll
  for (int off = 32; off > 0; off >>= 1) {
    p += __shfl_down(p, off);
    q += __shfl_down(q, off);
  }
  __shared__ int red[8];
  __shared__ int baseS, totS;
  if (lane == 0) { red[wave] = p; red[4 + wave] = q; }
  __syncthreads();
  if (t == 0) {
    baseS = red[0] + red[1] + red[2] + red[3];
    totS  = red[4] + red[5] + red[6] + red[7];
  }
  __syncthreads();
  int i = blockIdx.x * 256 + t;
  int v = (i < n) ? din[i] : 0;
  __shared__ int tmp[256];
  tmp[t] = v;
  __syncthreads();
  for (int off = 1; off < 256; off <<= 1) {
    int x = (t >= off) ? tmp[t - off] : 0;
    __syncthreads();
    tmp[t] += x;
    __syncthreads();
  }
  if (i < n) rp[i] = tmp[t] - v + baseS;
  if (blockIdx.x == gridDim.x - 1 && t == 0) rp[n] = totS;
}

// ---------------- CSR fill, atomic-free; wse = w * onorm[src] * inorm[dst] ----------------
__global__ void fill_kernel(const int* __restrict__ src, const int* __restrict__ dst,
                            const float* __restrict__ w, const float* __restrict__ onorm,
                            const float* __restrict__ inorm,
                            const int* __restrict__ rp, const int* __restrict__ rank,
                            int* __restrict__ col, float* __restrict__ wse, int E) {
  int e = blockIdx.x * 256 + threadIdx.x;
  if (e < E) {
    int d = dst[e], s = src[e];
    int pos = rp[d] + rank[e];
    col[pos] = s;
    wse[pos] = w[e] * onorm[s] * inorm[d];
  }
}

// ---------------- SpMM (R5-best form + 8-edge unroll) ----------------
template <int RELU, int NU>
__global__ __launch_bounds__(64) void spmm_bf16(
    const unsigned short* __restrict__ feat, int ldf,
    const int* __restrict__ rp, const int* __restrict__ col,
    const float* __restrict__ wse,
    unsigned short* __restrict__ out, int ldo) {
  int v = blockIdx.x;
  int t = threadIdx.x;  // 64
  int beg = rp[v], end = rp[v + 1];
  float acc[2 * NU];
#pragma unroll
  for (int i = 0; i < 2 * NU; i++) acc[i] = 0.f;
  const unsigned short* base = feat + t * (2 * NU);
  int e = beg;
  for (; e + 8 <= end; e += 8) {
    int s[8]; float ww[8];
#pragma unroll
    for (int k = 0; k < 8; k++) { s[k] = col[e + k]; ww[k] = wse[e + k]; }
    unsigned u[8][NU];
#pragma unroll
    for (int k = 0; k < 8; k++) {
      const unsigned* pr = (const unsigned*)&base[(size_t)s[k] * ldf];
      if (NU == 2) { uint2 q = *(const uint2*)pr; u[k][0] = q.x; u[k][NU - 1] = q.y; }
      else u[k][0] = pr[0];
    }
#pragma unroll
    for (int k = 0; k < 8; k++)
#pragma unroll
      for (int j = 0; j < NU; j++) {
        acc[2 * j]     += ww[k] * bf_lo(u[k][j]);
        acc[2 * j + 1] += ww[k] * bf_hi(u[k][j]);
      }
  }
  for (; e < end; e++) {
    float w0 = wse[e];
    const unsigned* pr = (const unsigned*)&base[(size_t)col[e] * ldf];
    unsigned u[NU];
    if (NU == 2) { uint2 q = *(const uint2*)pr; u[0] = q.x; u[NU - 1] = q.y; }
    else u[0] = pr[0];
#pragma unroll
    for (int j = 0; j < NU; j++) {
      acc[2 * j]     += w0 * bf_lo(u[j]);
      acc[2 * j + 1] += w0 * bf_hi(u[j]);
    }
  }
  unsigned o[NU];
#pragma unroll
  for (int j = 0; j < NU; j++) {
    float a = acc[2 * j], b = acc[2 * j + 1];
    if (RELU) { a = fmaxf(a, 0.f); b = fmaxf(b, 0.f); }
    o[j] = (unsigned)f2bf(a) | ((unsigned)f2bf(b) << 16);
  }
  unsigned* po = (unsigned*)&out[(size_t)v * ldo + t * (2 * NU)];
  if (NU == 2) *(uint2*)po = make_uint2(o[0], o[NU - 1]);
  else po[0] = o[0];
}

// ---------------- MFMA GEMM body: BK=32 (proven R5/R9 form) ----------------
__device__ __forceinline__ void gemm_body(
    const unsigned short* __restrict__ A, int lda,
    const unsigned short* __restrict__ Bt, int K,
    unsigned short* __restrict__ C, int ldc, int col_off, int M,
    int relu,
    unsigned short* As, unsigned short* Bs) {
  const int tid = threadIdx.x;
  const int lane = tid & 63;
  const int w = tid >> 6;
  const int wm = w >> 1, wn = w & 1;
  const int m0 = blockIdx.x * 128;
  const int n0 = blockIdx.y * 128;
  const int q = lane >> 4;
  const int r16 = lane & 15;

  f32x4 acc[4][4];
#pragma unroll
  for (int i = 0; i < 4; i++)
#pragma unroll
    for (int j = 0; j < 4; j++) acc[i][j] = (f32x4){0.f, 0.f, 0.f, 0.f};

  const int ta = 2 * w, tb = 2 * w + 1;
  int gma = m0 + ta * 16 + r16; if (gma >= M) gma = M - 1;
  int gmb = m0 + tb * 16 + r16; if (gmb >= M) gmb = M - 1;
  const int gna = n0 + ta * 16 + r16;
  const int gnb = n0 + tb * 16 + r16;
  const unsigned short* pa = A + (size_t)gma * lda + q * 8;
  const unsigned short* pb = A + (size_t)gmb * lda + q * 8;
  const unsigned short* pc = Bt + (size_t)gna * K + q * 8;
  const unsigned short* pd = Bt + (size_t)gnb * K + q * 8;

  for (int k0 = 0; k0 < K; k0 += 32) {
    __syncthreads();
    gl_lds16(pa + k0, &As[ta * 512 + lane * 8]);
    gl_lds16(pb + k0, &As[tb * 512 + lane * 8]);
    gl_lds16(pc + k0, &Bs[ta * 512 + lane * 8]);
    gl_lds16(pd + k0, &Bs[tb * 512 + lane * 8]);
    __syncthreads();

    bf16x8 af[4], bfr[4];
#pragma unroll
    for (int i = 0; i < 4; i++)
      af[i] = *(const bf16x8*)&As[(wm * 4 + i) * 512 + lane * 8];
#pragma unroll
    for (int j = 0; j < 4; j++)
      bfr[j] = *(const bf16x8*)&Bs[(wn * 4 + j) * 512 + lane * 8];
#pragma unroll
    for (int i = 0; i < 4; i++)
#pragma unroll
      for (int j = 0; j < 4; j++)
        acc[i][j] = __builtin_amdgcn_mfma_f32_16x16x32_bf16(af[i], bfr[j], acc[i][j], 0, 0, 0);
  }

#pragma unroll
  for (int i = 0; i < 4; i++) {
    int rbase = m0 + (wm * 4 + i) * 16 + q * 4;
#pragma unroll
    for (int r = 0; r < 4; r++) {
      int gm = rbase + r;
      if (gm >= M) continue;
#pragma unroll
      for (int j = 0; j < 4; j++) {
        float v = acc[i][j][r];
        if (relu) v = fmaxf(v, 0.f);
        int gn = col_off + n0 + (wn * 4 + j) * 16 + r16;
        C[(size_t)gm * ldc + gn] = f2bf(v);
      }
    }
  }
}

// fused conv1-GEMM (z=0) + fc-GEMM (z=1)
__global__ __launch_bounds__(256) void gemm12_kernel(
    const unsigned short* __restrict__ A0, const unsigned short* __restrict__ B0,
    const unsigned short* __restrict__ A1, const unsigned short* __restrict__ B1,
    unsigned short* __restrict__ C, int M) {
  __shared__ unsigned short As[8 * 512];
  __shared__ unsigned short Bs[8 * 512];
  int z = blockIdx.z;
  gemm_body(z ? A1 : A0, 128, z ? B1 : B0, 128, C, 512, z * 256, M, z == 0, As, Bs);
}

__global__ __launch_bounds__(256) void gemm_kernel(
    const unsigned short* __restrict__ A, int lda,
    const unsigned short* __restrict__ Bt, int K,
    unsigned short* __restrict__ C, int ldc, int M, int relu) {
  __shared__ unsigned short As[8 * 512];
  __shared__ unsigned short Bs[8 * 512];
  gemm_body(A, lda, Bt, K, C, ldc, 0, M, relu, As, Bs);
}

// ---------------- LayerNorm + relu (bf16 in/out, fp32 stats) ----------------
__global__ void ln_relu_bf16(unsigned short* __restrict__ h, int ld,
                             const float* __restrict__ gamma,
                             const float* __restrict__ beta) {
  int v = blockIdx.x;
  int f = threadIdx.x;  // 256
  float val = bf_lo((unsigned)h[(size_t)v * ld + f]);
  float s = val, qq = val * val;
#pragma unroll
  for (int off = 32; off > 0; off >>= 1) {
    s += __shfl_down(s, off);
    qq += __shfl_down(qq, off);
  }
  __shared__ float ws_[5], wq_[5];
  int wave = f >> 6, lane = f & 63;
  if (lane == 0) { ws_[wave] = s; wq_[wave] = qq; }
  __syncthreads();
  if (f == 0) {
    float S = 0, Q = 0;
    for (int i = 0; i < 4; i++) { S += ws_[i]; Q += wq_[i]; }
    ws_[4] = S; wq_[4] = Q;
  }
  __syncthreads();
  float mean = ws_[4] * (1.f / 256.f);
  float var = wq_[4] * (1.f / 256.f) - mean * mean;
  float y = (val - mean) * rsqrtf(var + EPSF) * gamma[f] + beta[f];
  h[(size_t)v * ld + f] = f2bf(y > 0.f ? y : 0.f);
}

// ---------------- per-graph readout (graph_ids sorted), x3 bf16 -> fp32 sums ----------------
__global__ void readout_kernel(const unsigned short* __restrict__ x3,
                               const int* __restrict__ gid,
                               float* __restrict__ out, int n) {
  int g = blockIdx.x;
  int part = blockIdx.y;  // 8 parts
  int f = threadIdx.x;    // 256
  int lo = 0, hi = n;
  while (lo < hi) { int mid = (lo + hi) >> 1; if (gid[mid] < g) lo = mid + 1; else hi = mid; }
  int s = lo;
  lo = s; hi = n;
  while (lo < hi) { int mid = (lo + hi) >> 1; if (gid[mid] < g + 1) lo = mid + 1; else hi = mid; }
  int e = lo;
  int len = e - s;
  if (len <= 0) return;
  int chunk = (len + 7) / 8;
  int cs = s + part * chunk;
  int ce = cs + chunk; if (ce > e) ce = e;
  if (cs >= ce) return;
  float acc = 0.f;
  for (int v = cs; v < ce; v++) acc += bf_lo((unsigned)x3[(size_t)v * 256 + f]);
  atomicAdd(&out[g * 256 + f], acc);
}

// ---------------- launch ----------------

extern "C" void kernel_launch(void* const* d_in, const int* in_sizes, int n_in,
                              void* d_out, int out_size, void* d_ws, size_t ws_size,
                              hipStream_t stream) {
  const float* x     = (const float*)d_in[0];
  const float* w     = (const float*)d_in[1];
  const float* W1    = (const float*)d_in[2];
  const float* Wfc   = (const float*)d_in[3];
  const float* gamma = (const float*)d_in[4];
  const float* beta  = (const float*)d_in[5];
  const float* W2    = (const float*)d_in[6];
  const float* W3    = (const float*)d_in[7];
  const int*   src   = (const int*)d_in[8];
  const int*   dst   = (const int*)d_in[9];
  const int*   gid   = (const int*)d_in[10];
  float* out = (float*)d_out;

  const int N = NN, E = NE;

  char* p = (char*)d_ws;
  auto alloc = [&](size_t bytes) {
    char* r = p;
    p += (bytes + 255) & ~(size_t)255;
    return r;
  };
  int*   deg_out = (int*)alloc((size_t)N * 4);
  int*   deg_in  = (int*)alloc((size_t)N * 4);   // contiguous after deg_out
  float* onorm   = (float*)alloc((size_t)N * 4);
  float* inorm   = (float*)alloc((size_t)N * 4);
  int*   row_ptr = (int*)alloc((size_t)(N + 1) * 4);
  int*   bsum    = (int*)alloc(256 * 4);
  int*   rank    = (int*)alloc((size_t)E * 4);
  int*   col     = (int*)alloc((size_t)E * 4);
  float* wse     = (float*)alloc((size_t)E * 4);
  unsigned short* xb    = (unsigned short*)alloc((size_t)N * 128 * 2);
  unsigned short* aggX  = (unsigned short*)alloc((size_t)N * 128 * 2);
  unsigned short* x1f1  = (unsigned short*)alloc((size_t)N * 512 * 2);
  unsigned short* y2    = (unsigned short*)alloc((size_t)N * 256 * 2);
  unsigned short* x2    = (unsigned short*)alloc((size_t)N * 256 * 2);
  unsigned short* aggx2 = (unsigned short*)alloc((size_t)N * 256 * 2);
  unsigned short* W1t   = (unsigned short*)alloc((size_t)256 * 128 * 2);
  unsigned short* Wfct  = (unsigned short*)alloc((size_t)256 * 128 * 2);
  unsigned short* W2t   = (unsigned short*)alloc((size_t)256 * 512 * 2);
  unsigned short* W3t   = (unsigned short*)alloc((size_t)256 * 256 * 2);
  unsigned short* x3 = x1f1;  // x1f1 dead after y2 GEMM; reuse storage (bf16 now)

  hipMemsetAsync(deg_out, 0, (size_t)((char*)onorm - (char*)deg_out), stream);
  hipMemsetAsync(out, 0, (size_t)NG * 256 * 4, stream);

  const int nbS = (N + 255) / 256;  // 196

  prep_kernel<<<DEGB + XB + WTB, 256, 0, stream>>>(src, dst, deg_out, deg_in, rank,
                                                   x, xb, W1, Wfc, W2, W3,
                                                   W1t, Wfct, W2t, W3t);
  norms_scan1<<<nbS, 256, 0, stream>>>(deg_out, deg_in, onorm, inorm, bsum, N);
  scan3_kernel<<<nbS, 256, 0, stream>>>(deg_in, bsum, row_ptr, N, nbS);
  fill_kernel<<<(E + 255) / 256, 256, 0, stream>>>(src, dst, w, onorm, inorm, row_ptr,
                                                   rank, col, wse, E);

  dim3 ggrid((N + 127) / 128, 2);       // 391 x 2
  dim3 ggridz((N + 127) / 128, 2, 2);   // 391 x 2 x 2 (z: which GEMM)

  // aggX' = agg(xb)  [norms folded into wse]
  spmm_bf16<0, 1><<<N, 64, 0, stream>>>(xb, 128, row_ptr, col, wse, aggX, 128);
  // z=0: x1 = relu(aggX'@W1) -> x1f1[:,0:256] ; z=1: f1pre = xb@Wfc -> x1f1[:,256:512]
  gemm12_kernel<<<ggridz, 256, 0, stream>>>(aggX, W1t, xb, Wfct, x1f1, N);
  // f1 = relu(LN(f1pre)) in place
  ln_relu_bf16<<<N, 256, 0, stream>>>(x1f1 + 256, 512, gamma, beta);
  // y2 = x1f1 @ W2
  gemm_kernel<<<ggrid, 256, 0, stream>>>(x1f1, 512, W2t, 512, y2, 256, N, 0);
  // x2 = relu(agg'(y2))
  spmm_bf16<1, 2><<<N, 64, 0, stream>>>(y2, 256, row_ptr, col, wse, x2, 256);
  // aggx2 = agg'(x2)
  spmm_bf16<0, 2><<<N, 64, 0, stream>>>(x2, 256, row_ptr, col, wse, aggx2, 256);
  // x3 = relu(aggx2 @ W3) bf16 (into x1f1's storage)
  gemm_kernel<<<ggrid, 256, 0, stream>>>(aggx2, 256, W3t, 256, x3, 256, N, 1);
  // readout
  readout_kernel<<<dim3(NG, 8), 256, 0, stream>>>(x3, gid, out, N);
}